// Round 6
// baseline (1916.569 us; speedup 1.0000x reference)
//
#include <hip/hip_runtime.h>
#include <hip/hip_bf16.h>
#include <math.h>

#define N 50000
#define E 600000
#define EPB 32     // edges per pass
#define LDK 104    // padded K stride (bf16 elems) for tp tiles

typedef __attribute__((ext_vector_type(8))) short short8;
typedef __attribute__((ext_vector_type(4))) float float4v;

__device__ __forceinline__ float silu_f(float x) { return x / (1.f + __expf(-x)); }
__device__ __forceinline__ float sigm_f(float x) { return 1.f / (1.f + __expf(-x)); }
__device__ __forceinline__ unsigned short f2bf(float f) {
  unsigned u = __float_as_uint(f);
  u += 0x7fff + ((u >> 16) & 1);   // RNE
  return (unsigned short)(u >> 16);
}
__device__ __forceinline__ unsigned f2bf2(float a, float b) {
  __hip_bfloat162 h = __float22bfloat162_rn(float2{a, b});
  return *(unsigned*)&h;
}
__device__ __forceinline__ float bf2f(unsigned short u) {
  return __uint_as_float(((unsigned)u) << 16);
}

// ---------------- Kernel A: MFMA lin1 (+ zero cnt) ----------------
// s1 = node_s@W1s/8 ; v1 = node_v x W1v /sqrt(32). 64 nodes/block.
__global__ __launch_bounds__(256, 4)
void k_lin1(const float* __restrict__ node_s, const float* __restrict__ node_v,
            const float* __restrict__ W1s, const float* __restrict__ W1v,
            float* __restrict__ s1, float* __restrict__ v1, int* __restrict__ cnt) {
  __shared__ unsigned short As[64 * 72];
  __shared__ unsigned short Av[192 * 40];
  __shared__ unsigned short Bs[64 * 72];   // Bs[ch][u] = W1s[u][ch]/8
  __shared__ unsigned short Bv[32 * 40];   // Bv[v][u]  = W1v[u][v]/sqrt(32)
  const int t = threadIdx.x;
  const int gtid = blockIdx.x * 256 + t;
  if (gtid < N) cnt[gtid] = 0;
  const int wave = t >> 6, lane = t & 63, lm = lane & 15, quad = lane >> 4;
  const int nbase = blockIdx.x * 64;

  for (int i = t; i < 4096; i += 256) {
    int u = i >> 6, ch = i & 63;
    Bs[ch * 72 + u] = f2bf(W1s[i] * 0.125f);
  }
  for (int i = t; i < 1024; i += 256) {
    int u = i >> 5, v = i & 31;
    Bv[v * 40 + u] = f2bf(W1v[i] * 0.17677669529663689f);
  }
  for (int i = t; i < 2048; i += 256) {
    int nl = i >> 5, u2 = (i & 31) * 2;
    int n = nbase + nl;
    float2 v2 = (n < N) ? *(const float2*)&node_s[(size_t)n * 64 + u2] : float2{0.f, 0.f};
    *(unsigned*)&As[nl * 72 + u2] = f2bf2(v2.x, v2.y);
  }
  for (int i = t; i < 6144; i += 256) {
    int nl = i / 96, r = i - nl * 96;
    int n = nbase + nl;
    float vv = (n < N) ? node_v[(size_t)n * 96 + r] : 0.f;
    int u = (r * 171) >> 9, c = r - 3 * u;
    Av[(nl * 3 + c) * 40 + u] = f2bf(vv);
  }
  __syncthreads();
  // s-GEMM: nt = wave fixed, mt = 0..3
  {
    short8 bs0 = *(const short8*)&Bs[(wave * 16 + lm) * 72 + quad * 8];
    short8 bs1 = *(const short8*)&Bs[(wave * 16 + lm) * 72 + 32 + quad * 8];
#pragma unroll
    for (int mt = 0; mt < 4; mt++) {
      float4v acc = {0.f, 0.f, 0.f, 0.f};
      short8 a0 = *(const short8*)&As[(mt * 16 + lm) * 72 + quad * 8];
      short8 a1 = *(const short8*)&As[(mt * 16 + lm) * 72 + 32 + quad * 8];
      acc = __builtin_amdgcn_mfma_f32_16x16x32_bf16(a0, bs0, acc, 0, 0, 0);
      acc = __builtin_amdgcn_mfma_f32_16x16x32_bf16(a1, bs1, acc, 0, 0, 0);
#pragma unroll
      for (int reg = 0; reg < 4; reg++) {
        const int n = nbase + mt * 16 + quad * 4 + reg;
        if (n < N) s1[(size_t)n * 64 + wave * 16 + lm] = acc[reg];
      }
    }
  }
  // v-GEMM: nt = wave&1, mt = (wave>>1) + 2s
  {
    short8 bv = *(const short8*)&Bv[((wave & 1) * 16 + lm) * 40 + quad * 8];
#pragma unroll
    for (int s = 0; s < 6; s++) {
      const int mt = (wave >> 1) + 2 * s;
      float4v acc = {0.f, 0.f, 0.f, 0.f};
      short8 a = *(const short8*)&Av[(mt * 16 + lm) * 40 + quad * 8];
      acc = __builtin_amdgcn_mfma_f32_16x16x32_bf16(a, bv, acc, 0, 0, 0);
      const int vcol = (wave & 1) * 16 + lm;
#pragma unroll
      for (int reg = 0; reg < 4; reg++) {
        const int rm = mt * 16 + quad * 4 + reg;
        const int nl = (rm * 171) >> 9, c = rm - 3 * nl;
        const int n = nbase + nl;
        if (n < N) v1[(size_t)n * 96 + vcol * 3 + c] = acc[reg];
      }
    }
  }
}

// ---------------- Kernel: hist + weight prep fused ----------------
#define HIST_BLKS 2344
__global__ void k_hist(const int* __restrict__ eidx, int* __restrict__ counts,
                       const float* __restrict__ Wsc0, const float* __restrict__ W3s,
                       const float* __restrict__ Wsc1, const float* __restrict__ W3v,
                       unsigned short* __restrict__ BT, unsigned short* __restrict__ B2T) {
  const int b = blockIdx.x;
  if (b < HIST_BLKS) {
    int e = b * 256 + threadIdx.x;
    if (e < E) atomicAdd(&counts[eidx[E + e]], 1);
  } else {
    int i = (b - HIST_BLKS) * 256 + threadIdx.x;
    if (i < 96 * 1088) {
      int j = i / 1088, k = i % 1088;
      float v;
      if (k < 1024) v = Wsc0[(size_t)k * 96 + j] * 0.03125f;
      else          v = W3s[(size_t)(k - 1024) * 96 + j] * 0.125f;
      BT[i] = f2bf(v);
    } else {
      int i2 = i - 96 * 1088;
      if (i2 < 32 * 576) {
        int w = i2 / 576, k = i2 % 576;
        float v = 0.f;
        if (k < 512)      v = Wsc1[(size_t)k * 32 + w] * 0.04419417382415922f;
        else if (k < 544) v = W3v[(size_t)(k - 512) * 32 + w] * 0.17677669529663689f;
        B2T[i2] = f2bf(v);
      }
    }
  }
}

__global__ __launch_bounds__(1024)
void k_scan(int* __restrict__ counts, int* __restrict__ row_ptr) {
  __shared__ int ssum[1024];
  const int t = threadIdx.x;
  const int CH = 49;
  int lo = t * CH, hi = min(lo + CH, N);
  int s = 0;
  for (int i = lo; i < hi; i++) s += counts[i];
  ssum[t] = s;
  __syncthreads();
  for (int off = 1; off < 1024; off <<= 1) {
    int v = (t >= off) ? ssum[t - off] : 0;
    __syncthreads();
    ssum[t] += v;
    __syncthreads();
  }
  int run = (t == 0) ? 0 : ssum[t - 1];
  for (int i = lo; i < hi; i++) {
    int c = counts[i];
    row_ptr[i] = run; run += c;
    counts[i] = 0;               // counts reused as write-offset by k_scatter
  }
  if (t == 1023) row_ptr[N] = ssum[1023];
}

__global__ void k_scatter(const int* __restrict__ eidx, const int* __restrict__ row_ptr,
                          int* __restrict__ woff, int* __restrict__ perm) {
  int e = blockIdx.x * 256 + threadIdx.x;
  if (e < E) {
    int d = eidx[E + e];
    int p = atomicAdd(&woff[d], 1);
    perm[row_ptr[d] + p] = e;
  }
}

// ---------------- Kernel B: streaming per-edge message via MFMA (EPB=32) ----------------
template<int STORE>
__global__ __launch_bounds__(256, 4)
void k_msg(const float* __restrict__ s1, const float* __restrict__ v1,
           const float* __restrict__ emb, const float* __restrict__ sh0g,
           const float* __restrict__ sh1g, const int* __restrict__ eidx,
           const float* __restrict__ Wm1, const float* __restrict__ Wm2,
           const float* __restrict__ W2s, const float* __restrict__ W2v,
           float* __restrict__ aggs, float* __restrict__ aggv,
           unsigned short* __restrict__ msgS, unsigned short* __restrict__ msgV) {
  __shared__ unsigned short tps[EPB * LDK];
  __shared__ unsigned short tpv[EPB * 3 * LDK];
  __shared__ float gat[EPB][33];
  __shared__ float hb[EPB][8];
  __shared__ float sh1b[EPB][4];
  __shared__ float sh0b[EPB];
  __shared__ int ssrc[EPB];
  __shared__ int sdst[EPB];
  __shared__ float wm2s[192 * 9];
  __shared__ float wm1s[64];

  const int t = threadIdx.x;
  const int wave = t >> 6, lane = t & 63;
  const int lm = lane & 15, quad = lane >> 4;
  const float isq96 = 0.10206207261596575f;

  for (int i = t; i < 192 * 8; i += 256) {
    int h = i / 192, c = i % 192;
    wm2s[c * 9 + h] = Wm2[i];
  }
  if (t < 64) wm1s[t] = Wm1[t];

  // ---- B-fragments in registers (isq96 folded) ----
  int mt1[3], nt1[3];
  short8 b1[3][3];
#pragma unroll
  for (int i = 0; i < 3; i++) {
    const int tile = wave + i * 4;
    mt1[i] = tile / 6; nt1[i] = tile % 6;
#pragma unroll
    for (int kk = 0; kk < 3; kk++) {
      unsigned short tmp[8];
#pragma unroll
      for (int ii = 0; ii < 8; ii++)
        tmp[ii] = f2bf(W2s[(kk * 32 + quad * 8 + ii) * 96 + nt1[i] * 16 + lm] * isq96);
      b1[i][kk] = *(short8*)tmp;
    }
  }
  const int nt2 = wave & 1;
  short8 b2[3];
#pragma unroll
  for (int kk = 0; kk < 3; kk++) {
    unsigned short tmp[8];
#pragma unroll
    for (int ii = 0; ii < 8; ii++)
      tmp[ii] = f2bf(W2v[(kk * 32 + quad * 8 + ii) * 32 + nt2 * 16 + lm] * isq96);
    b2[kk] = *(short8*)tmp;
  }
  __syncthreads();

  for (int pass = blockIdx.x; pass < E / EPB; pass += gridDim.x) {
    const int ebase = pass * EPB;
    // ---- phase A: MLP hidden (all threads) + meta staging (disjoint) ----
    {
      const int el = t >> 3, sub = t & 7;
      float acc = 0.f;
#pragma unroll
      for (int r = 0; r < 8; r++) acc += emb[(size_t)(ebase + el) * 8 + r] * wm1s[r * 8 + sub];
      hb[el][sub] = silu_f(acc);
      if (t < EPB) {
        ssrc[t] = eidx[ebase + t];
        if (!STORE) sdst[t] = eidx[E + ebase + t];
        sh0b[t] = sh0g[ebase + t];
      } else if (t >= 64 && t < 64 + EPB * 3) {
        int i = t - 64;
        sh1b[i / 3][i % 3] = sh1g[(size_t)ebase * 3 + i];
      }
    }
    __syncthreads();
    // ---- phase B: build TPS / TPV (bf16, packed cvt), 2 edges/thread ----
    const int sub = t & 15;
#pragma unroll
    for (int half = 0; half < 2; half++) {
      const int el = (t >> 4) + half * 16;
      const int src = ssrc[el];
      const float s0v = sh0b[el];
      const float x0 = sh1b[el][0], x1 = sh1b[el][1], x2 = sh1b[el][2];
      float hr[8];
#pragma unroll
      for (int h = 0; h < 8; h++) hr[h] = hb[el][h];
      const float4v ss = *(const float4v*)&s1[(size_t)src * 64 + sub * 4];
      float ts[4], tv[3][4];
#pragma unroll
      for (int i = 0; i < 4; i++) {
        float w0a = 0.f, w1a = 0.f;
#pragma unroll
        for (int h = 0; h < 8; h++) {
          w0a += hr[h] * wm2s[(sub * 4 + i) * 9 + h];
          w1a += hr[h] * wm2s[(64 + sub * 4 + i) * 9 + h];
        }
        const float ssu = ss[i];
        ts[i] = w0a * ssu * s0v;
        const float base = w1a * ssu;
        tv[0][i] = base * x0; tv[1][i] = base * x1; tv[2][i] = base * x2;
      }
      {
        unsigned p[2] = {f2bf2(ts[0], ts[1]), f2bf2(ts[2], ts[3])};
        *(uint2*)&tps[el * LDK + sub * 4] = *(uint2*)p;
      }
#pragma unroll
      for (int c = 0; c < 3; c++) {
        unsigned p[2] = {f2bf2(tv[c][0], tv[c][1]), f2bf2(tv[c][2], tv[c][3])};
        *(uint2*)&tpv[(el * 3 + c) * LDK + sub * 4] = *(uint2*)p;
      }
      const float2* vp = (const float2*)&v1[(size_t)src * 96 + sub * 6];
      const float2 va = vp[0], vb = vp[1], vc = vp[2];
      const float v6[6] = {va.x, va.y, vb.x, vb.y, vc.x, vc.y};
      float t2s[2], t2v[3][2];
#pragma unroll
      for (int i2 = 0; i2 < 2; i2++) {
        float w1b = 0.f, w0b = 0.f;
#pragma unroll
        for (int h = 0; h < 8; h++) {
          w1b += hr[h] * wm2s[(128 + sub * 2 + i2) * 9 + h];
          w0b += hr[h] * wm2s[(160 + sub * 2 + i2) * 9 + h];
        }
        const float vx = v6[i2 * 3 + 0], vy = v6[i2 * 3 + 1], vz = v6[i2 * 3 + 2];
        t2s[i2] = w0b * (vx * x0 + vy * x1 + vz * x2);
        t2v[0][i2] = w1b * vx * s0v; t2v[1][i2] = w1b * vy * s0v; t2v[2][i2] = w1b * vz * s0v;
      }
      *(unsigned*)&tps[el * LDK + 64 + sub * 2] = f2bf2(t2s[0], t2s[1]);
#pragma unroll
      for (int c = 0; c < 3; c++)
        *(unsigned*)&tpv[(el * 3 + c) * LDK + 64 + sub * 2] = f2bf2(t2v[c][0], t2v[c][1]);
    }
    __syncthreads();
    // ---- GEMM1: m_s[32][96] ----
    {
      short8 afr[2][3];
#pragma unroll
      for (int mt = 0; mt < 2; mt++)
#pragma unroll
        for (int kk = 0; kk < 3; kk++)
          afr[mt][kk] = *(const short8*)&tps[(mt * 16 + lm) * LDK + kk * 32 + quad * 8];
#pragma unroll
      for (int i = 0; i < 3; i++) {
        float4v acc = {0.f, 0.f, 0.f, 0.f};
#pragma unroll
        for (int kk = 0; kk < 3; kk++)
          acc = __builtin_amdgcn_mfma_f32_16x16x32_bf16(afr[mt1[i]][kk], b1[i][kk], acc, 0, 0, 0);
        const int j = nt1[i] * 16 + lm;
#pragma unroll
        for (int reg = 0; reg < 4; reg++) {
          const int e = mt1[i] * 16 + quad * 4 + reg;
          const float val = acc[reg];
          if (j < 64) {
            if (STORE) msgS[(size_t)(ebase + e) * 64 + j] = f2bf(silu_f(val));
            else atomicAdd(&aggs[(size_t)sdst[e] * 64 + j], silu_f(val));
          } else {
            gat[e][j - 64] = sigm_f(val);
          }
        }
      }
    }
    __syncthreads();
    // ---- GEMM2: m_v[96][32] ----
#pragma unroll
    for (int i = 0; i < 3; i++) {
      const int mt = (wave >> 1) + i * 2;
      float4v acc = {0.f, 0.f, 0.f, 0.f};
#pragma unroll
      for (int kk = 0; kk < 3; kk++) {
        short8 a = *(const short8*)&tpv[(mt * 16 + lm) * LDK + kk * 32 + quad * 8];
        acc = __builtin_amdgcn_mfma_f32_16x16x32_bf16(a, b2[kk], acc, 0, 0, 0);
      }
      const int v = nt2 * 16 + lm;
#pragma unroll
      for (int reg = 0; reg < 4; reg++) {
        const int r = mt * 16 + quad * 4 + reg;
        const int e = (r * 171) >> 9, c = r - 3 * e;
        const float val = acc[reg] * gat[e][v];
        if (STORE) msgV[(size_t)(ebase + e) * 96 + v * 3 + c] = f2bf(val);
        else atomicAdd(&aggv[(size_t)sdst[e] * 96 + v * 3 + c], val);
      }
    }
    __syncthreads();
  }
}

// ---------------- Kernel B2: wave-per-node gather-reduction via perm ----------------
__global__ __launch_bounds__(256, 8)
void k_agg(const unsigned short* __restrict__ msgS, const unsigned short* __restrict__ msgV,
           const int* __restrict__ rowp, const int* __restrict__ perm,
           float* __restrict__ aggs, float* __restrict__ aggv) {
  const int wv = threadIdx.x >> 6, lane = threadIdx.x & 63;
  const int n = blockIdx.x * 4 + wv;
  const int lo = rowp[n], hi = rowp[n + 1];
  float sS = 0.f, v0 = 0.f, v1a = 0.f;
  int r = lo;
  for (; r + 2 <= hi; r += 2) {
    const int e0 = perm[r], e1 = perm[r + 1];
    const unsigned short a0 = msgS[(size_t)e0 * 64 + lane];
    const unsigned short a1 = msgS[(size_t)e1 * 64 + lane];
    const unsigned short b0 = msgV[(size_t)e0 * 96 + lane];
    const unsigned short b1 = msgV[(size_t)e1 * 96 + lane];
    unsigned short c0 = 0, c1 = 0;
    if (lane < 32) {
      c0 = msgV[(size_t)e0 * 96 + 64 + lane];
      c1 = msgV[(size_t)e1 * 96 + 64 + lane];
    }
    sS += bf2f(a0) + bf2f(a1);
    v0 += bf2f(b0) + bf2f(b1);
    v1a += bf2f(c0) + bf2f(c1);
  }
  for (; r < hi; r++) {
    const int e0 = perm[r];
    sS += bf2f(msgS[(size_t)e0 * 64 + lane]);
    v0 += bf2f(msgV[(size_t)e0 * 96 + lane]);
    if (lane < 32) v1a += bf2f(msgV[(size_t)e0 * 96 + 64 + lane]);
  }
  aggs[(size_t)n * 64 + lane] = sS;
  aggv[(size_t)n * 96 + lane] = v0;
  if (lane < 32) aggv[(size_t)n * 96 + 64 + lane] = v1a;
}

// ---------------- Kernel C1: MFMA GEMM  [32 nodes x 1088] @ BT^T -> 96 cols ----------------
__global__ __launch_bounds__(256, 4)
void k_c1(const float* __restrict__ node_s, const float* __restrict__ attrs,
          const float* __restrict__ aggs, const float* __restrict__ Wt0,
          const unsigned short* __restrict__ BT,
          float* __restrict__ out, float* __restrict__ gates) {
  __shared__ float s_row[32][64];
  __shared__ float attr[32][16];
  __shared__ float t0[32][64];
  __shared__ float wt0[1024];
  __shared__ unsigned short As[32 * 72];
  const int t = threadIdx.x;
  const int wave = t >> 6, lane = t & 63, lm = lane & 15, quad = lane >> 4;
  const int nbase = blockIdx.x * 32;

  for (int i = t; i < 1024; i += 256) wt0[i] = Wt0[i];
  for (int i = t; i < 2048; i += 256) {
    int nl = i >> 6, u = i & 63, n = nbase + nl;
    s_row[nl][u] = (n < N) ? node_s[(size_t)n * 64 + u] : 0.f;
    t0[nl][u]    = (n < N) ? aggs[(size_t)n * 64 + u] : 0.f;
  }
  for (int i = t; i < 512; i += 256) {
    int nl = i >> 4, a = i & 15, n = nbase + nl;
    attr[nl][a] = (n < N) ? attrs[(size_t)n * 16 + a] : 0.f;
  }
  __syncthreads();
  for (int i = t; i < 2048; i += 256) {
    int nl = i >> 6, u = i & 63;
    float d0 = 0.f;
#pragma unroll
    for (int a = 0; a < 16; a++) d0 += attr[nl][a] * wt0[u * 16 + a];
    t0[nl][u] *= d0 * 0.07216878364870322f;
  }

  float4v acc[3] = {{0,0,0,0},{0,0,0,0},{0,0,0,0}};
  int mts[3], nts[3];
#pragma unroll
  for (int tt = 0; tt < 3; tt++) {
    const int tile = wave + tt * 4;
    mts[tt] = tile / 6;
    nts[tt] = tile % 6;
  }

  for (int kc = 0; kc < 17; kc++) {
    __syncthreads();
    {
      const int row = t >> 3, c0 = (t & 7) * 8;
      unsigned p[4];
      if (kc < 16) {
        const int u = kc * 4 + (c0 >> 4);
        const float sval = s_row[row][u];
        const int ab = c0 & 8;
#pragma unroll
        for (int i2 = 0; i2 < 4; i2++)
          p[i2] = f2bf2(sval * attr[row][ab + 2 * i2], sval * attr[row][ab + 2 * i2 + 1]);
      } else {
#pragma unroll
        for (int i2 = 0; i2 < 4; i2++)
          p[i2] = f2bf2(t0[row][c0 + 2 * i2], t0[row][c0 + 2 * i2 + 1]);
      }
      *(uint4*)&As[row * 72 + c0] = *(uint4*)p;
    }
    __syncthreads();
#pragma unroll
    for (int ks = 0; ks < 2; ks++) {
      short8 am0 = *(const short8*)&As[(lm) * 72 + ks * 32 + quad * 8];
      short8 am1 = *(const short8*)&As[(16 + lm) * 72 + ks * 32 + quad * 8];
#pragma unroll
      for (int tt = 0; tt < 3; tt++) {
        short8 b = *(const short8*)&BT[(size_t)(nts[tt] * 16 + lm) * 1088 + kc * 64 + ks * 32 + quad * 8];
        acc[tt] = __builtin_amdgcn_mfma_f32_16x16x32_bf16(mts[tt] ? am1 : am0, b, acc[tt], 0, 0, 0);
      }
    }
  }
#pragma unroll
  for (int tt = 0; tt < 3; tt++) {
    const int j = nts[tt] * 16 + lm;
#pragma unroll
    for (int reg = 0; reg < 4; reg++) {
      const int m = mts[tt] * 16 + quad * 4 + reg;
      const int n = nbase + m;
      if (n < N) {
        const float val = acc[tt][reg];
        if (j < 64) out[(size_t)n * 160 + j] = silu_f(val);
        else        gates[(size_t)n * 32 + (j - 64)] = sigm_f(val);
      }
    }
  }
}

// ---------------- Kernel C2: MFMA GEMM  [96 rows x 544] @ B2T^T -> 32 cols ----------------
__global__ __launch_bounds__(256, 3)
void k_c2(const float* __restrict__ node_v, const float* __restrict__ attrs,
          const float* __restrict__ aggv, const float* __restrict__ Wt1,
          const unsigned short* __restrict__ B2T, const float* __restrict__ gts,
          float* __restrict__ out) {
  __shared__ float nvs[32][96];
  __shared__ float t1s[32][96];
  __shared__ float attr[32][16];
  __shared__ float wt1[512];
  __shared__ unsigned short As2[96 * 72];
  const int t = threadIdx.x;
  const int wave = t >> 6, lane = t & 63, lm = lane & 15, quad = lane >> 4;
  const int nbase = blockIdx.x * 32;

  for (int i = t; i < 512; i += 256) wt1[i] = Wt1[i];
  for (int i = t; i < 32 * 96; i += 256) {
    int nl = i / 96, rr = i % 96, n = nbase + nl;
    nvs[nl][rr] = (n < N) ? node_v[(size_t)n * 96 + rr] : 0.f;
    t1s[nl][rr] = (n < N) ? aggv[(size_t)n * 96 + rr] : 0.f;
  }
  for (int i = t; i < 512; i += 256) {
    int nl = i >> 4, a = i & 15, n = nbase + nl;
    attr[nl][a] = (n < N) ? attrs[(size_t)n * 16 + a] : 0.f;
  }
  __syncthreads();
  for (int i = t; i < 1024; i += 256) {
    int nl = i >> 5, u = i & 31;
    float d1 = 0.f;
#pragma unroll
    for (int a = 0; a < 16; a++) d1 += attr[nl][a] * wt1[u * 16 + a];
    d1 *= 0.07216878364870322f;
    t1s[nl][u * 3 + 0] *= d1; t1s[nl][u * 3 + 1] *= d1; t1s[nl][u * 3 + 2] *= d1;
  }

  float4v acc[3] = {{0,0,0,0},{0,0,0,0},{0,0,0,0}};
  int mts[3], nts[3];
#pragma unroll
  for (int tt = 0; tt < 3; tt++) {
    const int tile = wave + tt * 4;
    mts[tt] = tile >> 1;
    nts[tt] = tile & 1;
  }

  for (int kc = 0; kc < 9; kc++) {
    __syncthreads();
#pragma unroll
    for (int jj = 0; jj < 3; jj++) {
      const int job = t + jj * 256;
      const int row = job >> 3, c0 = (job & 7) * 8;
      const int nl = (row * 171) >> 9, c = row - 3 * nl;
      const int kbase = kc * 64 + c0;
      unsigned p[4];
      if (kbase < 512) {
        const int u = kbase >> 4;
        const float vval = nvs[nl][u * 3 + c];
        const int ab = c0 & 8;
#pragma unroll
        for (int i2 = 0; i2 < 4; i2++)
          p[i2] = f2bf2(vval * attr[nl][ab + 2 * i2], vval * attr[nl][ab + 2 * i2 + 1]);
      } else if (kbase < 544) {
        const int u2 = kbase - 512;
#pragma unroll
        for (int i2 = 0; i2 < 4; i2++)
          p[i2] = f2bf2(t1s[nl][(u2 + 2 * i2) * 3 + c], t1s[nl][(u2 + 2 * i2 + 1) * 3 + c]);
      } else {
#pragma unroll
        for (int i2 = 0; i2 < 4; i2++) p[i2] = 0;
      }
      *(uint4*)&As2[row * 72 + c0] = *(uint4*)p;
    }
    __syncthreads();
#pragma unroll
    for (int ks = 0; ks < 2; ks++) {
#pragma unroll
      for (int tt = 0; tt < 3; tt++) {
        short8 a = *(const short8*)&As2[(mts[tt] * 16 + lm) * 72 + ks * 32 + quad * 8];
        short8 b = *(const short8*)&B2T[(size_t)(nts[tt] * 16 + lm) * 576 + kc * 64 + ks * 32 + quad * 8];
        acc[tt] = __builtin_amdgcn_mfma_f32_16x16x32_bf16(a, b, acc[tt], 0, 0, 0);
      }
    }
  }
#pragma unroll
  for (int tt = 0; tt < 3; tt++) {
    const int w = nts[tt] * 16 + lm;
#pragma unroll
    for (int reg = 0; reg < 4; reg++) {
      const int row = mts[tt] * 16 + quad * 4 + reg;
      const int nl = (row * 171) >> 9, c = row - 3 * nl;
      const int n = nbase + nl;
      if (n < N)
        out[(size_t)n * 160 + 64 + w * 3 + c] = acc[tt][reg] * gts[(size_t)n * 32 + w];
    }
  }
}

extern "C" void kernel_launch(void* const* d_in, const int* in_sizes, int n_in,
                              void* d_out, int out_size, void* d_ws, size_t ws_size,
                              hipStream_t stream) {
  const float* node_s = (const float*)d_in[0];
  const float* node_v = (const float*)d_in[1];
  const float* attrs  = (const float*)d_in[2];
  const float* emb    = (const float*)d_in[3];
  const float* sh0    = (const float*)d_in[4];
  const float* sh1    = (const float*)d_in[5];
  const int*   eidx   = (const int*)d_in[6];
  const float* W1s    = (const float*)d_in[7];
  const float* W1v    = (const float*)d_in[8];
  const float* Wm1    = (const float*)d_in[9];
  const float* Wm2    = (const float*)d_in[10];
  const float* W2s    = (const float*)d_in[11];
  const float* W2v    = (const float*)d_in[12];
  const float* Wt0    = (const float*)d_in[13];
  const float* Wt1    = (const float*)d_in[14];
  const float* W3s    = (const float*)d_in[15];
  const float* W3v    = (const float*)d_in[16];
  const float* Wsc0   = (const float*)d_in[17];
  const float* Wsc1   = (const float*)d_in[18];

  char* p = (char*)d_ws;
  float* s1  = (float*)p;  p += (size_t)N * 64 * 4;
  float* v1f = (float*)p;  p += (size_t)N * 96 * 4;
  float* gts = (float*)p;  p += (size_t)N * 32 * 4;
  unsigned short* BT  = (unsigned short*)p;  p += (size_t)96 * 1088 * 2;
  unsigned short* B2T = (unsigned short*)p;  p += (size_t)32 * 576 * 2;
  int* rowp = (int*)p;     p += ((size_t)N + 1) * 4;
  int* cnt  = (int*)p;     p += (size_t)N * 4;
  char* pmode = p;
  size_t base = (size_t)(pmode - (char*)d_ws);
  size_t need_store = base + (size_t)E * 4 + (size_t)E * 64 * 2 + (size_t)E * 96 * 2;
  const bool store = (ws_size >= need_store);

  k_lin1<<<782, 256, 0, stream>>>(node_s, node_v, W1s, W1v, s1, v1f, cnt);
  k_hist<<<HIST_BLKS + 480, 256, 0, stream>>>(eidx, cnt, Wsc0, W3s, Wsc1, W3v, BT, B2T);
  k_scan<<<1, 1024, 0, stream>>>(cnt, rowp);

  if (store) {
    int* perm = (int*)pmode;
    unsigned short* msgS = (unsigned short*)(perm + E);
    unsigned short* msgV = msgS + (size_t)E * 64;
    k_scatter<<<(E + 255) / 256, 256, 0, stream>>>(eidx, rowp, cnt, perm);
    k_msg<1><<<1536, 256, 0, stream>>>(s1, v1f, emb, sh0, sh1, eidx, Wm1, Wm2, W2s, W2v,
                                       nullptr, nullptr, msgS, msgV);
    float* aggs = s1;    // s1/v1 dead after k_msg: alias
    float* aggv = v1f;
    k_agg<<<N / 4, 256, 0, stream>>>(msgS, msgV, rowp, perm, aggs, aggv);
    k_c1<<<1563, 256, 0, stream>>>(node_s, attrs, aggs, Wt0, BT, (float*)d_out, gts);
    k_c2<<<1563, 256, 0, stream>>>(node_v, attrs, aggv, Wt1, B2T, gts, (float*)d_out);
  } else {
    float* aggs = (float*)pmode;
    float* aggv = aggs + (size_t)N * 64;
    hipMemsetAsync(aggs, 0, (size_t)N * 160 * 4, stream);
    k_msg<0><<<1536, 256, 0, stream>>>(s1, v1f, emb, sh0, sh1, eidx, Wm1, Wm2, W2s, W2v,
                                       aggs, aggv, nullptr, nullptr);
    k_c1<<<1563, 256, 0, stream>>>(node_s, attrs, aggs, Wt0, BT, (float*)d_out, gts);
    k_c2<<<1563, 256, 0, stream>>>(node_v, attrs, aggv, Wt1, B2T, gts, (float*)d_out);
  }
}